// Round 2
// baseline (191.219 us; speedup 1.0000x reference)
//
#include <hip/hip_runtime.h>
#include <math.h>

#define S_LEN    16
#define BATCH_N  4
#define NTOK     64     // tokens, m = s*4 + b
#define DMODEL   512
#define XB_COLS  2176   // x part (2048) + B part (128); z and C parts are dead code
#define ZX_COLS  2240   // XB_COLS + 64 dt columns
#define NCLASS   2513
#define FEATDIM  4096

// ---------------- Phase A (fused): in_proj dot + conv/silu (+ dt/dA) ----------------
// Grid (18,4), 256 thr = 4 waves. Wave w: rows r0 = by*16 + w*4 .. +3 (X loads wave-
// uniform -> 1 line/txn). Lane: 2 consecutive cols j0,j1 of the 2240 needed columns.
// Full K=512 per thread (no split-K, no partials). Epilogue applies the 4 conv prefix
// weights + silu and writes u[k][m][c] (coalesced in c), or softplus/exp for dt cols.
__global__ __launch_bounds__(256) void k_front(const float* __restrict__ X,
                                               const float* __restrict__ W,
                                               const float* __restrict__ conv_w,
                                               const float* __restrict__ conv_b,
                                               const float* __restrict__ dt_bias,
                                               const float* __restrict__ A_log,
                                               float* __restrict__ u,
                                               float* __restrict__ aArr,
                                               float* __restrict__ dArr) {
    const int tid  = threadIdx.x;
    const int lane = tid & 63;
    const int wv   = tid >> 6;
    const int j0   = blockIdx.x * 128 + lane * 2;
    const int j1   = j0 + 1;
    const bool v0  = j0 < ZX_COLS;
    const bool v1  = j1 < ZX_COLS;
    const int e0   = (j0 < XB_COLS) ? (2048 + j0) : (2176 + j0);
    const int e1   = (j1 < XB_COLS) ? (2048 + j1) : (2176 + j1);
    const float* wp0 = W + (size_t)(v0 ? e0 : 0) * DMODEL;
    const float* wp1 = W + (size_t)(v1 ? e1 : 0) * DMODEL;
    const int r0 = blockIdx.y * 16 + wv * 4;

    float acc0[4], acc1[4];
#pragma unroll
    for (int r = 0; r < 4; ++r) { acc0[r] = 0.f; acc1[r] = 0.f; }

    for (int k = 0; k < DMODEL; k += 4) {
        const float4 wa = *reinterpret_cast<const float4*>(wp0 + k);
        const float4 wb = *reinterpret_cast<const float4*>(wp1 + k);
#pragma unroll
        for (int r = 0; r < 4; ++r) {
            const int m = r0 + r;
            const float4 av = *reinterpret_cast<const float4*>(
                X + (size_t)(m & 3) * (S_LEN * DMODEL) + (size_t)(m >> 2) * DMODEL + k);
            acc0[r] += av.x * wa.x + av.y * wa.y + av.z * wa.z + av.w * wa.w;
            acc1[r] += av.x * wb.x + av.y * wb.y + av.z * wb.z + av.w * wb.w;
        }
    }

#pragma unroll
    for (int col = 0; col < 2; ++col) {
        const int j = (col == 0) ? j0 : j1;
        const bool valid = (col == 0) ? v0 : v1;
        if (!valid) continue;
        const float* accp = (col == 0) ? acc0 : acc1;
        if (j < XB_COLS) {
            const float4 cwv = *reinterpret_cast<const float4*>(conv_w + j * 4);
            const float cb = conv_b[j];
            float wk[4];
            wk[0] = cwv.w;                 // cw[:,0] = conv_w[:,3]
            wk[1] = wk[0] + cwv.z;
            wk[2] = wk[1] + cwv.y;
            wk[3] = wk[2] + cwv.x;
#pragma unroll
            for (int r = 0; r < 4; ++r) {
                const int m = r0 + r;
#pragma unroll
                for (int k = 0; k < 4; ++k) {
                    const float v = accp[r] * wk[k] + cb;
                    u[((size_t)k * NTOK + m) * XB_COLS + j] = v / (1.f + expf(-v));
                }
            }
        } else {
            const int h = j - XB_COLS;
            const float ae = expf(A_log[h]);
            const float db = dt_bias[h];
#pragma unroll
            for (int r = 0; r < 4; ++r) {
                const int m = r0 + r;
                const float x = accp[r] + db;
                const float d = (x > 20.f) ? x : log1pf(expf(x));
                dArr[m * 64 + h] = d;
                aArr[m * 64 + h] = expf(-d * ae);
            }
        }
    }
}

// ---------------- Phase C: collapsed SSM -> feats[b*16+t][4096] ------------------
__global__ __launch_bounds__(256) void k_feats(const float* __restrict__ u,
                                               const float* __restrict__ aArr,
                                               const float* __restrict__ dArr,
                                               float* __restrict__ feats) {
    const int t = blockIdx.x >> 2;
    const int b = blockIdx.x & 3;
    const int tid = threadIdx.x;
    const int K = 16 - t;          // unroll updates k = 0..K
    const int nvec = t + 5;        // (t+1) scan vectors + 4 unroll vectors

    __shared__ float q[16][64];    // scan coefs per (s,h)
    __shared__ float cu[4][64];    // unroll coefs per (k,h)
    __shared__ float WV[20][32];
    __shared__ float Bv[20][128];

    if (tid < 64) {
        const int h = tid;
        const int mt = t * 4 + b;
        const float a   = aArr[mt * 64 + h];
        const float dtv = dArr[mt * 64 + h];
        float p = 1.f;
        float c3 = 0.f, c2 = 0.f, c1 = 0.f, c0 = 0.f, cs = 0.f;
        for (int j = 0; j <= K + 1; ++j) {     // p = a^j at loop head
            if (j <= K - 3) c3 += p;           // geometric sum for k=3..K
            if (j == K - 2) c2 = p;
            if (j == K - 1) c1 = p;
            if (j == K)     c0 = p;
            if (j == K + 1) cs = p;            // multiplies states[t]
            p *= a;
        }
        cu[0][h] = dtv * c0;
        cu[1][h] = dtv * c1;
        cu[2][h] = dtv * c2;
        cu[3][h] = dtv * c3;
        float prod = 1.f;                      // prod_{j=s+1..t} a_j
        for (int s = t; s >= 0; --s) {
            const int ms = s * 4 + b;
            q[s][h] = cs * prod * dArr[ms * 64 + h];
            prod *= aArr[ms * 64 + h];
        }
    }
    __syncthreads();

    {   // head-reduced x vectors (32 wide each)
        const int i = tid & 31;
        const int vs = tid >> 5;
        for (int v = vs; v < nvec; v += 8) {
            float acc = 0.f;
            if (v <= t) {
                const float* base = u + (size_t)(v * 4 + b) * XB_COLS;   // u0[s=v]
                for (int h = 0; h < 64; ++h) acc += q[v][h] * base[h * 32 + i];
            } else {
                const int kk = v - t - 1;
                const float* base = u + ((size_t)kk * NTOK + t * 4 + b) * XB_COLS;
                for (int h = 0; h < 64; ++h) acc += cu[kk][h] * base[h * 32 + i];
            }
            WV[v][i] = acc;
        }
    }
    // B vectors (128 wide each)
    for (int x = tid; x < nvec * 128; x += 256) {
        const int v = x >> 7, n = x & 127;
        size_t src;
        if (v <= t) src = (size_t)(v * 4 + b) * XB_COLS + 2048 + n;
        else        src = ((size_t)(v - t - 1) * NTOK + t * 4 + b) * XB_COLS + 2048 + n;
        Bv[v][n] = u[src];
    }
    __syncthreads();

    {   // rank-nvec outer-product accumulation -> feats
        const int i  = tid >> 3;
        const int n0 = (tid & 7) * 16;
        float acc[16];
#pragma unroll
        for (int nn = 0; nn < 16; ++nn) acc[nn] = 0.f;
        for (int v = 0; v < nvec; ++v) {
            const float wvv = WV[v][i];
#pragma unroll
            for (int nn = 0; nn < 16; ++nn) acc[nn] += wvv * Bv[v][n0 + nn];
        }
        float* dst = feats + (size_t)(b * 16 + t) * FEATDIM + i * 128 + n0;
#pragma unroll
        for (int nn = 0; nn < 16; ++nn) dst[nn] = acc[nn] * (1.f / 64.f);
    }
}

// ---------------- Phase D: classifier GEMM (64 x 2513, K=4096), split-K = gridDim.y --
__global__ __launch_bounds__(512) void k_cls(const float* __restrict__ feats,
                                             const float* __restrict__ Wc,
                                             float* __restrict__ partialD) {
    const int tid  = threadIdx.x;
    const int lane = tid & 63;
    const int wv   = tid >> 6;
    const int c0 = blockIdx.x * 128 + lane * 2;
    const int c1 = c0 + 1;
    const bool v0 = c0 < NCLASS, v1 = c1 < NCLASS;
    const float* wp0 = Wc + (size_t)(v0 ? c0 : 0) * FEATDIM;
    const float* wp1 = Wc + (size_t)(v1 ? c1 : 0) * FEATDIM;
    const int chunk = FEATDIM / gridDim.y;
    const int k0 = blockIdx.y * chunk;
    const int r0 = wv * 8;

    float acc0[8], acc1[8];
#pragma unroll
    for (int r = 0; r < 8; ++r) { acc0[r] = 0.f; acc1[r] = 0.f; }

    for (int k = k0; k < k0 + chunk; k += 4) {
        const float4 wa = *reinterpret_cast<const float4*>(wp0 + k);
        const float4 wb = *reinterpret_cast<const float4*>(wp1 + k);
#pragma unroll
        for (int r = 0; r < 8; ++r) {
            const float4 av = *reinterpret_cast<const float4*>(
                feats + (size_t)(r0 + r) * FEATDIM + k);
            acc0[r] += av.x * wa.x + av.y * wa.y + av.z * wa.z + av.w * wa.w;
            acc1[r] += av.x * wb.x + av.y * wb.y + av.z * wb.z + av.w * wb.w;
        }
    }
#pragma unroll
    for (int r = 0; r < 8; ++r) {
        float* dst = partialD + ((size_t)blockIdx.y * NTOK + r0 + r) * NCLASS;
        if (v0) dst[c0] = acc0[r];
        if (v1) dst[c1] = acc1[r];
    }
}

__global__ void k_out(const float* __restrict__ partialD, const float* __restrict__ cls_b,
                      float* __restrict__ out, int KC) {
    const int idx = blockIdx.x * 256 + threadIdx.x;
    if (idx >= NTOK * NCLASS) return;
    const int c = idx % NCLASS;
    float s = cls_b[c];
    for (int k = 0; k < KC; ++k) s += partialD[(size_t)k * (NTOK * NCLASS) + idx];
    out[idx] = s;   // row r = b*16 + t matches output (B,S,C) layout
}

// ------------------------------------------------------------------------------
extern "C" void kernel_launch(void* const* d_in, const int* in_sizes, int n_in,
                              void* d_out, int out_size, void* d_ws, size_t ws_size,
                              hipStream_t stream) {
    const float* inputs  = (const float*)d_in[0];
    const float* in_proj = (const float*)d_in[1];
    const float* conv_w  = (const float*)d_in[2];
    const float* conv_b  = (const float*)d_in[3];
    const float* dt_bias = (const float*)d_in[4];
    const float* A_log   = (const float*)d_in[5];
    const float* cls_w   = (const float*)d_in[6];
    const float* cls_b   = (const float*)d_in[7];
    float* out = (float*)d_out;

    float* ws = (float*)d_ws;
    float* aArr  = ws;                       //  4096
    float* dArr  = ws + 4096;                //  4096
    float* feats = ws + 8192;                //  262144
    float* scr   = ws + 270336;              //  scratch, time-shared:
    float* u        = scr;                   //    u: 4*64*2176 = 557056 (dead after k_feats)
    float* partialD = scr;                   //    partialD: KC*64*2513 (written after k_feats)

    // choose classifier split-K to fit ws_size (all tiers verified-fitting):
    //   KC=16 -> (270336 + 2573312)*4 = 11,374,592 B
    //   KC=8  -> (270336 + 1286656)*4 =  6,227,968 B
    //   KC=4  -> (270336 +  643328)*4 =  3,654,656 B
    //   KC=2  -> (270336 +  557056)*4 =  3,309,568 B   (u is the floor)
    int KC;
    if      (ws_size >= 11374592u) KC = 16;
    else if (ws_size >=  6227968u) KC = 8;
    else if (ws_size >=  3654656u) KC = 4;
    else                           KC = 2;

    k_front <<<dim3(18, 4), 256, 0, stream>>>(inputs, in_proj, conv_w, conv_b,
                                              dt_bias, A_log, u, aArr, dArr);
    k_feats <<<64, 256, 0, stream>>>(u, aArr, dArr, feats);
    k_cls   <<<dim3(20, KC), 512, 0, stream>>>(feats, cls_w, partialD);
    k_out   <<<629, 256, 0, stream>>>(partialD, cls_b, out, KC);
}

// Round 3
// 159.239 us; speedup vs baseline: 1.2008x; 1.2008x over previous
//
#include <hip/hip_runtime.h>
#include <math.h>

#define S_LEN    16
#define NTOK     64     // tokens, m = s*4 + b (lane dimension everywhere)
#define DMODEL   512
#define XB_COLS  2176   // x part (2048) + B part (128); z and C parts are dead code
#define ZX_COLS  2240   // XB_COLS + 64 dt columns
#define NCLASS   2513
#define FEATDIM  4096

// ---------------- k_xt: X (B,S,D) -> k-panel layout Xtp[(k/4)][m][4] -------------
__global__ void k_xt(const float* __restrict__ X, float* __restrict__ Xtp) {
    const int i = blockIdx.x * 256 + threadIdx.x;   // 8192 = 128 quads * 64 tokens
    const int kq = i >> 6, m = i & 63;
    const int row = (m & 3) * 16 + (m >> 2);        // inputs row b*16+s for token m=s*4+b
    const float4 v = *reinterpret_cast<const float4*>(X + (size_t)row * DMODEL + kq * 4);
    *reinterpret_cast<float4*>(Xtp + (size_t)i * 4) = v;
}

// ---------------- k_front: in_proj dots + conv/silu + dt/dA ----------------------
// lane = token (coalesced Xtp loads); wave owns 2 columns (wave-uniform W rows).
// grid.x = 280 (8 cols per block of 4 waves), full K=512 per thread.
__global__ __launch_bounds__(256) void k_front(const float* __restrict__ Xtp,
                                               const float* __restrict__ W,
                                               const float* __restrict__ conv_w,
                                               const float* __restrict__ conv_b,
                                               const float* __restrict__ dt_bias,
                                               const float* __restrict__ A_log,
                                               float* __restrict__ u,
                                               float* __restrict__ aArr,
                                               float* __restrict__ dArr) {
    const int lane = threadIdx.x & 63;          // token m
    const int wv   = threadIdx.x >> 6;
    const int j0   = blockIdx.x * 8 + wv * 2;   // [0,2240) exact
    const int e0   = (j0     < XB_COLS) ? (2048 + j0)     : (2176 + j0);
    const int e1   = (j0 + 1 < XB_COLS) ? (2048 + j0 + 1) : (2176 + j0 + 1);
    const float* wp0 = W + (size_t)e0 * DMODEL;
    const float* wp1 = W + (size_t)e1 * DMODEL;

    float a0 = 0.f, a1 = 0.f;
    for (int kq = 0; kq < DMODEL / 4; ++kq) {
        const float4 f  = *reinterpret_cast<const float4*>(Xtp + ((size_t)kq * 64 + lane) * 4);
        const float4 w0 = *reinterpret_cast<const float4*>(wp0 + kq * 4);
        const float4 w1 = *reinterpret_cast<const float4*>(wp1 + kq * 4);
        a0 += f.x * w0.x + f.y * w0.y + f.z * w0.z + f.w * w0.w;
        a1 += f.x * w1.x + f.y * w1.y + f.z * w1.z + f.w * w1.w;
    }

#pragma unroll
    for (int col = 0; col < 2; ++col) {
        const int j = j0 + col;
        const float acc = (col == 0) ? a0 : a1;
        if (j < XB_COLS) {
            const float4 cwv = *reinterpret_cast<const float4*>(conv_w + j * 4);
            const float cb = conv_b[j];
            float wk[4];
            wk[0] = cwv.w;                  // cw[:,0] = conv_w[:,3]
            wk[1] = wk[0] + cwv.z;
            wk[2] = wk[1] + cwv.y;
            wk[3] = wk[2] + cwv.x;
#pragma unroll
            for (int k = 0; k < 4; ++k) {
                const float v = acc * wk[k] + cb;
                u[((size_t)k * NTOK + lane) * XB_COLS + j] = v / (1.f + expf(-v));
            }
        } else {
            const int h = j - XB_COLS;
            const float x = acc + dt_bias[h];
            const float d = (x > 20.f) ? x : log1pf(expf(x));
            dArr[lane * 64 + h] = d;
            aArr[lane * 64 + h] = expf(-d * expf(A_log[h]));
        }
    }
}

// ---------------- k_feats: collapsed SSM -> feats in k-panel layout ---------------
__global__ __launch_bounds__(256) void k_feats(const float* __restrict__ u,
                                               const float* __restrict__ aArr,
                                               const float* __restrict__ dArr,
                                               float* __restrict__ feats_p) {
    const int t = blockIdx.x >> 2;
    const int b = blockIdx.x & 3;
    const int tid = threadIdx.x;
    const int K = 16 - t;          // unroll updates k = 0..K
    const int nvec = t + 5;        // (t+1) scan vectors + 4 unroll vectors

    __shared__ float q[16][64];
    __shared__ float cu[4][64];
    __shared__ float WV[20][32];
    __shared__ float Bv[20][128];

    if (tid < 64) {
        const int h = tid;
        const int mt = t * 4 + b;
        const float a   = aArr[mt * 64 + h];
        const float dtv = dArr[mt * 64 + h];
        float p = 1.f;
        float c3 = 0.f, c2 = 0.f, c1 = 0.f, c0 = 0.f, cs = 0.f;
        for (int j = 0; j <= K + 1; ++j) {     // p = a^j at loop head
            if (j <= K - 3) c3 += p;
            if (j == K - 2) c2 = p;
            if (j == K - 1) c1 = p;
            if (j == K)     c0 = p;
            if (j == K + 1) cs = p;
            p *= a;
        }
        cu[0][h] = dtv * c0;
        cu[1][h] = dtv * c1;
        cu[2][h] = dtv * c2;
        cu[3][h] = dtv * c3;
        float prod = 1.f;
        for (int s = t; s >= 0; --s) {
            const int ms = s * 4 + b;
            q[s][h] = cs * prod * dArr[ms * 64 + h];
            prod *= aArr[ms * 64 + h];
        }
    }
    __syncthreads();

    {   // head-reduced x vectors (32 wide each)
        const int i = tid & 31;
        const int vs = tid >> 5;
        for (int v = vs; v < nvec; v += 8) {
            float acc = 0.f;
            if (v <= t) {
                const float* base = u + (size_t)(v * 4 + b) * XB_COLS;
                for (int h = 0; h < 64; ++h) acc += q[v][h] * base[h * 32 + i];
            } else {
                const int kk = v - t - 1;
                const float* base = u + ((size_t)kk * NTOK + t * 4 + b) * XB_COLS;
                for (int h = 0; h < 64; ++h) acc += cu[kk][h] * base[h * 32 + i];
            }
            WV[v][i] = acc;
        }
    }
    for (int x = tid; x < nvec * 128; x += 256) {
        const int v = x >> 7, n = x & 127;
        size_t src;
        if (v <= t) src = (size_t)(v * 4 + b) * XB_COLS + 2048 + n;
        else        src = ((size_t)(v - t - 1) * NTOK + t * 4 + b) * XB_COLS + 2048 + n;
        Bv[v][n] = u[src];
    }
    __syncthreads();

    {   // rank-nvec outer products -> feats panel [k/4][64 rows][4]
        const int i  = tid >> 3;            // headdim index 0..31
        const int n0 = (tid & 7) * 16;      // state offset
        const int r  = b * 16 + t;          // output row (matches out layout)
        float acc[16];
#pragma unroll
        for (int nn = 0; nn < 16; ++nn) acc[nn] = 0.f;
        for (int v = 0; v < nvec; ++v) {
            const float wvv = WV[v][i];
#pragma unroll
            for (int nn = 0; nn < 16; ++nn) acc[nn] += wvv * Bv[v][n0 + nn];
        }
        float4* fp4 = reinterpret_cast<float4*>(feats_p);
#pragma unroll
        for (int qq = 0; qq < 4; ++qq) {
            // k = i*128 + n0 + qq*4 + {0..3}  ->  quad index kq
            const int kq = i * 32 + (tid & 7) * 4 + qq;
            float4 v4;
            v4.x = acc[qq * 4 + 0] * (1.f / 64.f);
            v4.y = acc[qq * 4 + 1] * (1.f / 64.f);
            v4.z = acc[qq * 4 + 2] * (1.f / 64.f);
            v4.w = acc[qq * 4 + 3] * (1.f / 64.f);
            fp4[(size_t)kq * 64 + r] = v4;
        }
    }
}

// ---------------- k_cls: classifier GEMM, lane=token, wave=16 classes -------------
// grid (40, KC).  Partials layout [kc][class][token] (all accesses lane-coalesced).
__global__ __launch_bounds__(256) void k_cls(const float* __restrict__ feats_p,
                                             const float* __restrict__ Wc,
                                             float* __restrict__ partialD) {
    const int lane  = threadIdx.x & 63;     // token / output row
    const int wv    = threadIdx.x >> 6;
    const int cbase = blockIdx.x * 64 + wv * 16;
    const int quadsPer = (FEATDIM / 4) / gridDim.y;
    const int kq0 = blockIdx.y * quadsPer;

    const float* wrow[16];
#pragma unroll
    for (int i = 0; i < 16; ++i) {
        const int c = cbase + i;
        wrow[i] = Wc + (size_t)(c > NCLASS - 1 ? NCLASS - 1 : c) * FEATDIM;
    }

    float acc[16];
#pragma unroll
    for (int i = 0; i < 16; ++i) acc[i] = 0.f;

    const float4* fp4 = reinterpret_cast<const float4*>(feats_p);
    for (int kq = kq0; kq < kq0 + quadsPer; ++kq) {
        const float4 f = fp4[(size_t)kq * 64 + lane];
#pragma unroll
        for (int i = 0; i < 16; ++i) {
            const float4 w = *reinterpret_cast<const float4*>(wrow[i] + kq * 4);
            acc[i] += f.x * w.x + f.y * w.y + f.z * w.z + f.w * w.w;
        }
    }
#pragma unroll
    for (int i = 0; i < 16; ++i) {
        const int c = cbase + i;
        if (c < NCLASS)
            partialD[((size_t)blockIdx.y * NCLASS + c) * 64 + lane] = acc[i];
    }
}

// ---------------- k_out: reduce split-K partials + bias -> out --------------------
__global__ void k_out(const float* __restrict__ partialD, const float* __restrict__ cls_b,
                      float* __restrict__ out, int KC) {
    const int r  = threadIdx.x & 63;
    const int cl = threadIdx.x >> 6;
    const int c  = blockIdx.x * 4 + cl;
    if (c >= NCLASS) return;
    float s = cls_b[c];
    for (int kc = 0; kc < KC; ++kc)
        s += partialD[((size_t)kc * NCLASS + c) * 64 + r];
    out[(size_t)r * NCLASS + c] = s;
}

// ------------------------------------------------------------------------------
extern "C" void kernel_launch(void* const* d_in, const int* in_sizes, int n_in,
                              void* d_out, int out_size, void* d_ws, size_t ws_size,
                              hipStream_t stream) {
    const float* inputs  = (const float*)d_in[0];
    const float* in_proj = (const float*)d_in[1];
    const float* conv_w  = (const float*)d_in[2];
    const float* conv_b  = (const float*)d_in[3];
    const float* dt_bias = (const float*)d_in[4];
    const float* A_log   = (const float*)d_in[5];
    const float* cls_w   = (const float*)d_in[6];
    const float* cls_b   = (const float*)d_in[7];
    float* out = (float*)d_out;

    float* ws = (float*)d_ws;
    float* aArr    = ws;               //   4096
    float* dArr    = ws + 4096;        //   4096
    float* Xtp     = ws + 8192;        //  32768
    float* feats_p = ws + 40960;       // 262144
    float* scr     = ws + 303104;      // time-shared: u (557056, dead after k_feats)
    float* u        = scr;             //              then partialD (KC*2513*64)
    float* partialD = scr;

    // split-K tier chosen to fit ws_size (bytes incl. 303104-float prefix):
    //   KC=16 -> 11,505,664   KC=8 -> 6,359,040   KC=4 -> 3,785,728   KC=2 -> 3,440,640
    int KC;
    if      (ws_size >= 11505664u) KC = 16;
    else if (ws_size >=  6359040u) KC = 8;
    else if (ws_size >=  3785728u) KC = 4;
    else                           KC = 2;

    k_xt    <<<32, 256, 0, stream>>>(inputs, Xtp);
    k_front <<<280, 256, 0, stream>>>(Xtp, in_proj, conv_w, conv_b,
                                      dt_bias, A_log, u, aArr, dArr);
    k_feats <<<64, 256, 0, stream>>>(u, aArr, dArr, feats_p);
    k_cls   <<<dim3(40, KC), 256, 0, stream>>>(feats_p, cls_w, partialD);
    k_out   <<<629, 256, 0, stream>>>(partialD, cls_b, out, KC);
}

// Round 4
// 97.190 us; speedup vs baseline: 1.9675x; 1.6384x over previous
//
#include <hip/hip_runtime.h>
#include <math.h>

#define S_LEN    16
#define NTOK     64     // tokens, m = s*4 + b (lane dimension everywhere)
#define DMODEL   512
#define XB_COLS  2176   // x part (2048) + B part (128); z and C parts are dead code
#define ZX_COLS  2240   // XB_COLS + 64 dt columns
#define NCLASS   2513
#define FEATDIM  4096

// ---------------- k_xt: X (B,S,D) -> k-panel layout Xtp[(k/4)][m][4] -------------
__global__ void k_xt(const float* __restrict__ X, float* __restrict__ Xtp) {
    const int i = blockIdx.x * 256 + threadIdx.x;   // 8192 = 128 quads * 64 tokens
    const int kq = i >> 6, m = i & 63;
    const int row = (m & 3) * 16 + (m >> 2);        // inputs row b*16+s for token m=s*4+b
    const float4 v = *reinterpret_cast<const float4*>(X + (size_t)row * DMODEL + kq * 4);
    *reinterpret_cast<float4*>(Xtp + (size_t)i * 4) = v;
}

// ---------------- k_fpart: in_proj partial dots (K split by gridDim.y) ------------
// lane = token; wave = 2 columns; K-window = 128/gridDim.y quads. Rolling prefetch.
__global__ __launch_bounds__(256) void k_fpart(const float* __restrict__ Xtp,
                                               const float* __restrict__ W,
                                               float* __restrict__ partF) {
    const int lane = threadIdx.x & 63;
    const int wv   = threadIdx.x >> 6;
    const int j0   = blockIdx.x * 8 + wv * 2;   // [0,2240)
    const int e0   = (j0     < XB_COLS) ? (2048 + j0)     : (2176 + j0);
    const int e1   = (j0 + 1 < XB_COLS) ? (2048 + j0 + 1) : (2176 + j0 + 1);
    const int nq   = 128 / gridDim.y;           // quads in this K-window
    const int q0   = blockIdx.y * nq;

    const float4* w0p = reinterpret_cast<const float4*>(W + (size_t)e0 * DMODEL) + q0;
    const float4* w1p = reinterpret_cast<const float4*>(W + (size_t)e1 * DMODEL) + q0;
    const float4* fp  = reinterpret_cast<const float4*>(Xtp) + (size_t)q0 * 64 + lane;

    float a0 = 0.f, a1 = 0.f;
    float4 f = fp[0], w0 = w0p[0], w1 = w1p[0];
    for (int i = 0; i < nq; ++i) {
        const float4 fc = f, wa = w0, wb = w1;
        if (i + 1 < nq) {                        // rolling prefetch
            f  = fp[(size_t)(i + 1) * 64];
            w0 = w0p[i + 1];
            w1 = w1p[i + 1];
        }
        a0 += fc.x * wa.x + fc.y * wa.y + fc.z * wa.z + fc.w * wa.w;
        a1 += fc.x * wb.x + fc.y * wb.y + fc.z * wb.z + fc.w * wb.w;
    }
    partF[((size_t)blockIdx.y * ZX_COLS + j0) * 64 + lane]     = a0;
    partF[((size_t)blockIdx.y * ZX_COLS + j0 + 1) * 64 + lane] = a1;
}

// ---------------- k_fepi: reduce partials + conv/silu + dt/dA ---------------------
__global__ __launch_bounds__(256) void k_fepi(const float* __restrict__ partF, int KF,
                                              const float* __restrict__ conv_w,
                                              const float* __restrict__ conv_b,
                                              const float* __restrict__ dt_bias,
                                              const float* __restrict__ A_log,
                                              float* __restrict__ u,
                                              float* __restrict__ aArr,
                                              float* __restrict__ dArr) {
    const int lane = threadIdx.x & 63;                 // token m
    const int j    = blockIdx.x * 4 + (threadIdx.x >> 6);
    float acc = 0.f;
    for (int kf = 0; kf < KF; ++kf)
        acc += partF[((size_t)kf * ZX_COLS + j) * 64 + lane];

    if (j < XB_COLS) {
        const float4 cwv = *reinterpret_cast<const float4*>(conv_w + j * 4);
        const float cb = conv_b[j];
        float wk[4];
        wk[0] = cwv.w;                  // cw[:,0] = conv_w[:,3]
        wk[1] = wk[0] + cwv.z;
        wk[2] = wk[1] + cwv.y;
        wk[3] = wk[2] + cwv.x;
#pragma unroll
        for (int k = 0; k < 4; ++k) {
            const float v = acc * wk[k] + cb;
            u[((size_t)k * NTOK + lane) * XB_COLS + j] = v / (1.f + expf(-v));
        }
    } else {
        const int h = j - XB_COLS;
        const float x = acc + dt_bias[h];
        const float d = (x > 20.f) ? x : log1pf(expf(x));
        dArr[lane * 64 + h] = d;
        aArr[lane * 64 + h] = expf(-d * expf(A_log[h]));
    }
}

// ---------------- k_feats: collapsed SSM -> feats in k-panel layout ---------------
__global__ __launch_bounds__(256) void k_feats(const float* __restrict__ u,
                                               const float* __restrict__ aArr,
                                               const float* __restrict__ dArr,
                                               float* __restrict__ feats_p) {
    const int t = blockIdx.x >> 2;
    const int b = blockIdx.x & 3;
    const int tid = threadIdx.x;
    const int K = 16 - t;          // unroll updates k = 0..K
    const int nvec = t + 5;        // (t+1) scan vectors + 4 unroll vectors

    __shared__ float q[16][64];
    __shared__ float cu[4][64];
    __shared__ float WV[20][32];
    __shared__ float Bv[20][128];

    if (tid < 64) {
        const int h = tid;
        const int mt = t * 4 + b;
        const float a   = aArr[mt * 64 + h];
        const float dtv = dArr[mt * 64 + h];
        float p = 1.f;
        float c3 = 0.f, c2 = 0.f, c1 = 0.f, c0 = 0.f, cs = 0.f;
        for (int j = 0; j <= K + 1; ++j) {     // p = a^j at loop head
            if (j <= K - 3) c3 += p;
            if (j == K - 2) c2 = p;
            if (j == K - 1) c1 = p;
            if (j == K)     c0 = p;
            if (j == K + 1) cs = p;
            p *= a;
        }
        cu[0][h] = dtv * c0;
        cu[1][h] = dtv * c1;
        cu[2][h] = dtv * c2;
        cu[3][h] = dtv * c3;
        float prod = 1.f;
        for (int s = t; s >= 0; --s) {
            const int ms = s * 4 + b;
            q[s][h] = cs * prod * dArr[ms * 64 + h];
            prod *= aArr[ms * 64 + h];
        }
    }
    __syncthreads();

    {   // head-reduced x vectors (32 wide each)
        const int i = tid & 31;
        const int vs = tid >> 5;
        for (int v = vs; v < nvec; v += 8) {
            float acc = 0.f;
            if (v <= t) {
                const float* base = u + (size_t)(v * 4 + b) * XB_COLS;
                for (int h = 0; h < 64; ++h) acc += q[v][h] * base[h * 32 + i];
            } else {
                const int kk = v - t - 1;
                const float* base = u + ((size_t)kk * NTOK + t * 4 + b) * XB_COLS;
                for (int h = 0; h < 64; ++h) acc += cu[kk][h] * base[h * 32 + i];
            }
            WV[v][i] = acc;
        }
    }
    for (int x = tid; x < nvec * 128; x += 256) {
        const int v = x >> 7, n = x & 127;
        size_t src;
        if (v <= t) src = (size_t)(v * 4 + b) * XB_COLS + 2048 + n;
        else        src = ((size_t)(v - t - 1) * NTOK + t * 4 + b) * XB_COLS + 2048 + n;
        Bv[v][n] = u[src];
    }
    __syncthreads();

    {   // rank-nvec outer products -> feats panel [k/4][64 rows][4]
        const int i  = tid >> 3;            // headdim index 0..31
        const int n0 = (tid & 7) * 16;      // state offset
        const int r  = b * 16 + t;          // output row (matches out layout)
        float acc[16];
#pragma unroll
        for (int nn = 0; nn < 16; ++nn) acc[nn] = 0.f;
        for (int v = 0; v < nvec; ++v) {
            const float wvv = WV[v][i];
#pragma unroll
            for (int nn = 0; nn < 16; ++nn) acc[nn] += wvv * Bv[v][n0 + nn];
        }
        float4* fp4 = reinterpret_cast<float4*>(feats_p);
#pragma unroll
        for (int qq = 0; qq < 4; ++qq) {
            const int kq = i * 32 + (tid & 7) * 4 + qq;
            float4 v4;
            v4.x = acc[qq * 4 + 0] * (1.f / 64.f);
            v4.y = acc[qq * 4 + 1] * (1.f / 64.f);
            v4.z = acc[qq * 4 + 2] * (1.f / 64.f);
            v4.w = acc[qq * 4 + 3] * (1.f / 64.f);
            fp4[(size_t)kq * 64 + r] = v4;
        }
    }
}

// ---------------- k_cls: classifier GEMM with LDS-staged weights ------------------
// Block: 256 thr = 4 waves, 32 classes (8/wave), K-chunk = 4096/gridDim.y.
// Weights staged in 64-k subtiles via coalesced float4 loads; consumer reads are
// LDS broadcasts. feats loads stay global (L1-hot, same addr for all 4 waves),
// prefetched one quad ahead. Partials [kc][class][token], lane-coalesced.
__global__ __launch_bounds__(256) void k_cls(const float* __restrict__ feats_p,
                                             const float* __restrict__ Wc,
                                             float* __restrict__ partialD) {
    const int tid  = threadIdx.x;
    const int lane = tid & 63;              // token / output row
    const int wv   = tid >> 6;
    const int cls0 = blockIdx.x * 32;       // block's first class
    const int qPer = (FEATDIM / 4) / gridDim.y;
    const int kq0  = blockIdx.y * qPer;
    const int nsub = qPer >> 4;             // subtiles of 16 quads (64 k)

    __shared__ float Wl[32][64];            // [class-in-block][k-in-subtile]

    float acc[8];
#pragma unroll
    for (int i = 0; i < 8; ++i) acc[i] = 0.f;

    const float4* fp4 = reinterpret_cast<const float4*>(feats_p);
    float4 fpre = fp4[(size_t)kq0 * 64 + lane];

    // staging map: slot s in [0,512): class = s>>4, kslot = s&15 (one float4 each)
    const int sc0 = tid >> 4, sk0 = tid & 15;            // slot tid
    const int sc1 = (tid + 256) >> 4, sk1 = tid & 15;    // slot tid+256
    int row0 = cls0 + sc0; if (row0 >= NCLASS) row0 = NCLASS - 1;
    int row1 = cls0 + sc1; if (row1 >= NCLASS) row1 = NCLASS - 1;

    for (int sub = 0; sub < nsub; ++sub) {
        const int kbase = (kq0 + sub * 16) * 4;          // first k of subtile
        __syncthreads();                                 // protect Wl reuse
        {
            const float4 wa = *reinterpret_cast<const float4*>(
                Wc + (size_t)row0 * FEATDIM + kbase + sk0 * 4);
            const float4 wb = *reinterpret_cast<const float4*>(
                Wc + (size_t)row1 * FEATDIM + kbase + sk1 * 4);
            *reinterpret_cast<float4*>(&Wl[sc0][sk0 * 4]) = wa;
            *reinterpret_cast<float4*>(&Wl[sc1][sk1 * 4]) = wb;
        }
        __syncthreads();

        for (int q = 0; q < 16; ++q) {
            const int kq = kq0 + sub * 16 + q;
            const float4 f = fpre;
            int kqn = kq + 1; if (kqn > (FEATDIM / 4) - 1) kqn = (FEATDIM / 4) - 1;
            fpre = fp4[(size_t)kqn * 64 + lane];
#pragma unroll
            for (int i = 0; i < 8; ++i) {
                const float4 w = *reinterpret_cast<const float4*>(&Wl[wv * 8 + i][q * 4]);
                acc[i] += f.x * w.x + f.y * w.y + f.z * w.z + f.w * w.w;
            }
        }
    }

#pragma unroll
    for (int i = 0; i < 8; ++i) {
        const int c = cls0 + wv * 8 + i;
        if (c < NCLASS)
            partialD[((size_t)blockIdx.y * NCLASS + c) * 64 + lane] = acc[i];
    }
}

// ---------------- k_out: reduce split-K partials + bias -> out --------------------
__global__ void k_out(const float* __restrict__ partialD, const float* __restrict__ cls_b,
                      float* __restrict__ out, int KC) {
    const int r  = threadIdx.x & 63;
    const int cl = threadIdx.x >> 6;
    const int c  = blockIdx.x * 4 + cl;
    if (c >= NCLASS) return;
    float s = cls_b[c];
    for (int kc = 0; kc < KC; ++kc)
        s += partialD[((size_t)kc * NCLASS + c) * 64 + r];
    out[(size_t)r * NCLASS + c] = s;
}

// ------------------------------------------------------------------------------
extern "C" void kernel_launch(void* const* d_in, const int* in_sizes, int n_in,
                              void* d_out, int out_size, void* d_ws, size_t ws_size,
                              hipStream_t stream) {
    const float* inputs  = (const float*)d_in[0];
    const float* in_proj = (const float*)d_in[1];
    const float* conv_w  = (const float*)d_in[2];
    const float* conv_b  = (const float*)d_in[3];
    const float* dt_bias = (const float*)d_in[4];
    const float* A_log   = (const float*)d_in[5];
    const float* cls_w   = (const float*)d_in[6];
    const float* cls_b   = (const float*)d_in[7];
    float* out = (float*)d_out;

    float* ws = (float*)d_ws;
    float* aArr    = ws;               //   4096
    float* dArr    = ws + 4096;        //   4096
    float* Xtp     = ws + 8192;        //  32768
    float* feats_p = ws + 40960;       // 262144
    float* scr     = ws + 303104;
    float* u       = scr;              // 557056 (dead after k_feats)
    float* partF   = scr + 557056;     // KF*2240*64 (dead after k_fepi)
    float* partialD = scr;             // KC*2513*64 (written after k_feats)

    // tiers: bytes = (303104 + max(557056 + KF*143360, KC*160832)) * 4
    //   KC=16,KF=8 -> 11,505,664 (proven fitting in round 3)
    //   KC=8, KF=8 ->  8,028,160
    //   KC=4, KF=4 ->  5,734,400
    //   KC=2, KF=2 ->  4,587,520
    int KC, KF;
    if      (ws_size >= 11505664u) { KC = 16; KF = 8; }
    else if (ws_size >=  8028160u) { KC = 8;  KF = 8; }
    else if (ws_size >=  5734400u) { KC = 4;  KF = 4; }
    else                           { KC = 2;  KF = 2; }

    k_xt    <<<32, 256, 0, stream>>>(inputs, Xtp);
    k_fpart <<<dim3(280, KF), 256, 0, stream>>>(Xtp, in_proj, partF);
    k_fepi  <<<560, 256, 0, stream>>>(partF, KF, conv_w, conv_b, dt_bias, A_log,
                                      u, aArr, dArr);
    k_feats <<<64, 256, 0, stream>>>(u, aArr, dArr, feats_p);
    k_cls   <<<dim3(79, KC), 256, 0, stream>>>(feats_p, cls_w, partialD);
    k_out   <<<629, 256, 0, stream>>>(partialD, cls_b, out, KC);
}